// Round 1
// baseline (6869.463 us; speedup 1.0000x reference)
//
#include <hip/hip_runtime.h>
#include <stdint.h>

#define B_ 8
#define T_ 256
#define V_ 32000
#define E_ 768
#define N_ 1024
#define M_ (B_*T_)      // 2048 rows, m = b*T + t
#define RG 32           // recurrence workgroups
#define WCOLS (N_/RG)   // 32 columns per WG
#define LDK 40          // padded LDS row stride (ushorts): 80 B = 5*16 -> aligned b128, 2-way banks

typedef __attribute__((ext_vector_type(8))) short short8;
typedef __attribute__((ext_vector_type(4))) float floatx4;

__device__ __forceinline__ unsigned short f2b(float x) {
  union { float f; unsigned u; } v; v.f = x;
  unsigned r = v.u + 0x7fffu + ((v.u >> 16) & 1u);  // RNE
  return (unsigned short)(r >> 16);
}

// ---------- gather embedding rows -> bf16 (M x E) ----------
__global__ __launch_bounds__(256) void k_gather(const int* __restrict__ ids,
                                                const float* __restrict__ emb,
                                                unsigned short* __restrict__ xg) {
  int m = blockIdx.x;
  long tok = ids[m];
  const float* src = emb + tok * (long)E_;
  unsigned short* dst = xg + (long)m * E_;
  for (int e = threadIdx.x; e < E_; e += 256) dst[e] = f2b(src[e]);
}

// ---------- transpose fp32 (R x C) -> bf16 (C x R) ----------
__global__ __launch_bounds__(256) void k_transpose(const float* __restrict__ src,
                                                   unsigned short* __restrict__ dst,
                                                   int R, int C) {
  __shared__ float t[32][33];
  int tx = threadIdx.x & 31, ty = threadIdx.x >> 5;  // 32x8
  int c0 = blockIdx.x * 32, r0 = blockIdx.y * 32;
  #pragma unroll
  for (int i = 0; i < 32; i += 8)
    t[ty + i][tx] = src[(long)(r0 + ty + i) * C + c0 + tx];
  __syncthreads();
  #pragma unroll
  for (int i = 0; i < 32; i += 8)
    dst[(long)(c0 + ty + i) * R + r0 + tx] = f2b(t[tx][ty + i]);
}

// ---------- bf16 MFMA GEMM: C[MxN] = A[MxK] * BT[NxK]^T ----------
// 128x128 tile, 256 thr = 4 waves in 2x2, each wave 4x4 frags of 16x16x32.
// EPI: 0 = f32 out + bias[col]; 1 = bf16 out; 2 = f32 out
template<int EPI>
__global__ __launch_bounds__(256) void k_gemm_bt(const unsigned short* __restrict__ A,
                                                 const unsigned short* __restrict__ BT,
                                                 void* __restrict__ Cout,
                                                 const float* __restrict__ bias,
                                                 int M, int N, int K) {
  __shared__ unsigned short lsA[128 * LDK];
  __shared__ unsigned short lsB[128 * LDK];
  const int tid = threadIdx.x;
  const long m0 = (long)blockIdx.y * 128;
  const long n0 = (long)blockIdx.x * 128;
  const int w = tid >> 6, l = tid & 63;
  const int wm = (w >> 1) * 64, wn = (w & 1) * 64;
  const int lm = l & 15, kq = l >> 4;
  floatx4 acc[4][4] = {};
  for (int k0 = 0; k0 < K; k0 += 32) {
    #pragma unroll
    for (int i = 0; i < 2; ++i) {   // stage 128x32 of A and BT (dims divide exactly)
      int flat = i * 256 + tid;
      int r = flat >> 2, q4 = flat & 3;
      *(uint4*)(&lsA[r * LDK + q4 * 8]) = *(const uint4*)(&A[(m0 + r) * K + k0 + q4 * 8]);
      *(uint4*)(&lsB[r * LDK + q4 * 8]) = *(const uint4*)(&BT[(n0 + r) * K + k0 + q4 * 8]);
    }
    __syncthreads();
    short8 af[4], bf[4];
    #pragma unroll
    for (int mf = 0; mf < 4; ++mf) af[mf] = *(const short8*)(&lsA[(wm + mf * 16 + lm) * LDK + kq * 8]);
    #pragma unroll
    for (int nf = 0; nf < 4; ++nf) bf[nf] = *(const short8*)(&lsB[(wn + nf * 16 + lm) * LDK + kq * 8]);
    #pragma unroll
    for (int mf = 0; mf < 4; ++mf)
      #pragma unroll
      for (int nf = 0; nf < 4; ++nf)
        acc[mf][nf] = __builtin_amdgcn_mfma_f32_16x16x32_bf16(af[mf], bf[nf], acc[mf][nf], 0, 0, 0);
    __syncthreads();
  }
  // C/D layout (m89-verified): col = lane&15, row = (lane>>4)*4 + reg
  #pragma unroll
  for (int mf = 0; mf < 4; ++mf)
    #pragma unroll
    for (int nf = 0; nf < 4; ++nf)
      #pragma unroll
      for (int r = 0; r < 4; ++r) {
        long row = m0 + wm + mf * 16 + kq * 4 + r;
        long col = n0 + wn + nf * 16 + lm;
        float v = acc[mf][nf][r];
        if (EPI == 0)      ((float*)Cout)[row * N + col] = v + bias[col];
        else if (EPI == 1) ((unsigned short*)Cout)[row * N + col] = f2b(v);
        else               ((float*)Cout)[row * N + col] = v;
      }
}

// ---------- device-scope monotonic barrier ----------
__device__ __forceinline__ void gbar(unsigned* ctr, unsigned target) {
  __syncthreads();
  if (threadIdx.x == 0) {
    __hip_atomic_fetch_add(ctr, 1u, __ATOMIC_RELEASE, __HIP_MEMORY_SCOPE_AGENT);
    while (__hip_atomic_load(ctr, __ATOMIC_ACQUIRE, __HIP_MEMORY_SCOPE_AGENT) < target)
      __builtin_amdgcn_s_sleep(2);
  }
  __syncthreads();
}

// ---------- persistent recurrence: 1024 sequential (8x1024)@(1024x1024) + tanh ----------
// 32 WGs; WG g owns columns [g*32, g*32+32). w_bb column-slice lives in REGISTERS as
// MFMA B-frags (loaded once). State u broadcast via global bf16 ping-pong buffers [16][1024].
__global__ __launch_bounds__(256) void k_recurrence(const float* __restrict__ xbuf,
                                                    const float* __restrict__ w_bb,
                                                    const float* __restrict__ b_bb,
                                                    unsigned short* __restrict__ u0,
                                                    unsigned short* __restrict__ u1,
                                                    float* __restrict__ sAll,
                                                    unsigned* __restrict__ ctr) {
  __shared__ unsigned short wT[WCOLS * 1032];  // [c][k] bf16, stride 1032 (2064 B = 129*16)
  __shared__ float red[4 * 2 * 16 * 16];       // per-wave partial C tiles
  __shared__ float bias_s[WCOLS];
  const int g = blockIdx.x;
  const int tid = threadIdx.x;
  { // stage transposed w_bb slice into LDS (coalesced 128 B reads)
    int c = tid & 31, k8 = tid >> 5;
    for (int k0 = 0; k0 < N_; k0 += 8) {
      int k = k0 + k8;
      wT[c * 1032 + k] = f2b(w_bb[(long)k * N_ + g * WCOLS + c]);
    }
    if (tid < WCOLS) bias_s[tid] = b_bb[g * WCOLS + tid];
  }
  const int b8 = tid >> 5, c32 = tid & 31;  // output mapping: 8 batch x 32 cols
  // init u0 = bf16(state0 + x_{t=0}) = bf16(x_0)
  u0[b8 * N_ + g * WCOLS + c32] = f2b(xbuf[((long)b8 * T_) * N_ + g * WCOLS + c32]);
  __syncthreads();
  const int w = tid >> 6, l = tid & 63;
  const int lm = l & 15, kq = l >> 4;
  // B-frags resident in registers for the whole kernel: wave w covers K in [w*256, w*256+256)
  short8 bfrag[2][8];
  #pragma unroll
  for (int nf = 0; nf < 2; ++nf)
    #pragma unroll
    for (int it = 0; it < 8; ++it)
      bfrag[nf][it] = *(const short8*)(&wT[(nf * 16 + lm) * 1032 + w * 256 + it * 32 + kq * 8]);
  __threadfence();
  gbar(ctr, RG);
  unsigned bar = 1;
  for (int step = 0; step < 4 * T_; ++step) {
    const unsigned short* src = (step & 1) ? u1 : u0;
    unsigned short* dst = (step & 1) ? u0 : u1;
    floatx4 acc0 = {}, acc1 = {};
    #pragma unroll
    for (int it = 0; it < 8; ++it) {
      short8 a = *(const short8*)(&src[lm * N_ + w * 256 + it * 32 + kq * 8]);  // rows 8..15 junk, ignored
      acc0 = __builtin_amdgcn_mfma_f32_16x16x32_bf16(a, bfrag[0][it], acc0, 0, 0, 0);
      acc1 = __builtin_amdgcn_mfma_f32_16x16x32_bf16(a, bfrag[1][it], acc1, 0, 0, 0);
    }
    #pragma unroll
    for (int r = 0; r < 4; ++r) {   // partial K sums -> LDS
      red[((w * 2 + 0) * 16 + kq * 4 + r) * 16 + lm] = acc0[r];
      red[((w * 2 + 1) * 16 + kq * 4 + r) * 16 + lm] = acc1[r];
    }
    __syncthreads();
    float sum = bias_s[c32];
    { int nf = c32 >> 4, cc = c32 & 15;
      #pragma unroll
      for (int ww = 0; ww < 4; ++ww) sum += red[((ww * 2 + nf) * 16 + b8) * 16 + cc]; }
    int t = step >> 2, ph = step & 3;
    float sv = tanhf(sum);
    if (ph == 3) {
      sAll[((long)b8 * T_ + t) * N_ + g * WCOLS + c32] = sv;          // fp32 state for LN
      if (t + 1 < T_) sv += xbuf[((long)b8 * T_ + t + 1) * N_ + g * WCOLS + c32];  // pulse inject
    }
    dst[b8 * N_ + g * WCOLS + c32] = f2b(sv);
    __threadfence();
    gbar(ctr, (++bar) * RG);
  }
}

// ---------- row layernorm (fp32 in, bf16 out) ----------
__global__ __launch_bounds__(256) void k_layernorm(const float* __restrict__ sAll,
                                                   const float* __restrict__ gamma,
                                                   const float* __restrict__ beta,
                                                   unsigned short* __restrict__ hln) {
  long m = blockIdx.x;
  const float* x = sAll + m * N_;
  float v[4], lsum = 0.f, lsq = 0.f;
  #pragma unroll
  for (int i = 0; i < 4; ++i) {
    v[i] = x[threadIdx.x + i * 256];
    lsum += v[i]; lsq += v[i] * v[i];
  }
  #pragma unroll
  for (int off = 32; off > 0; off >>= 1) {
    lsum += __shfl_down(lsum, off);
    lsq  += __shfl_down(lsq, off);
  }
  __shared__ float sa[4], sb[4];
  int w = threadIdx.x >> 6, l = threadIdx.x & 63;
  if (l == 0) { sa[w] = lsum; sb[w] = lsq; }
  __syncthreads();
  float tsum = sa[0] + sa[1] + sa[2] + sa[3];
  float tsq  = sb[0] + sb[1] + sb[2] + sb[3];
  float mean = tsum * (1.f / N_);
  float var  = tsq * (1.f / N_) - mean * mean;   // population var (ddof=0), matches jnp.var
  float rst  = rsqrtf(var + 1e-5f);
  #pragma unroll
  for (int i = 0; i < 4; ++i) {
    int n = threadIdx.x + i * 256;
    hln[m * N_ + n] = f2b((v[i] - mean) * rst * gamma[n] + beta[n]);
  }
}

extern "C" void kernel_launch(void* const* d_in, const int* in_sizes, int n_in,
                              void* d_out, int out_size, void* d_ws, size_t ws_size,
                              hipStream_t stream) {
  const int*   ids    = (const int*)d_in[0];
  const float* emb    = (const float*)d_in[1];
  const float* w_in   = (const float*)d_in[2];
  const float* b_in   = (const float*)d_in[3];
  const float* w_bb   = (const float*)d_in[4];
  const float* b_bb   = (const float*)d_in[5];
  const float* gamma  = (const float*)d_in[6];
  const float* beta   = (const float*)d_in[7];
  const float* w_out  = (const float*)d_in[8];
  const float* w_head = (const float*)d_in[9];
  float* out = (float*)d_out;

  char* p = (char*)d_ws;
  size_t off = 0;
  auto alloc = [&](size_t bytes) { void* r = p + off; off += (bytes + 255) & ~(size_t)255; return r; };
  unsigned*       ctr     = (unsigned*)alloc(256);
  unsigned short* xg      = (unsigned short*)alloc((size_t)M_ * E_ * 2);   // gathered emb, bf16
  unsigned short* w_inT   = (unsigned short*)alloc((size_t)N_ * E_ * 2);   // [N][E]
  unsigned short* w_outT  = (unsigned short*)alloc((size_t)E_ * N_ * 2);   // [E][N]
  unsigned short* w_headT = (unsigned short*)alloc((size_t)V_ * E_ * 2);   // [V][E]
  float*          xbuf    = (float*)alloc((size_t)M_ * N_ * 4);            // x = emb@w_in + b_in
  unsigned short* u0      = (unsigned short*)alloc(16 * N_ * 2);           // state ping
  unsigned short* u1      = (unsigned short*)alloc(16 * N_ * 2);           // state pong
  float*          sAll    = (float*)alloc((size_t)M_ * N_ * 4);            // final state per (b,t)
  unsigned short* hln     = (unsigned short*)alloc((size_t)M_ * N_ * 2);   // LN(s) bf16
  unsigned short* hw      = (unsigned short*)alloc((size_t)M_ * E_ * 2);   // h @ w_out bf16

  hipMemsetAsync(ctr, 0, 256, stream);                                     // barrier counter = 0
  k_gather<<<M_, 256, 0, stream>>>(ids, emb, xg);
  k_transpose<<<dim3(N_ / 32, E_ / 32), 256, 0, stream>>>(w_in, w_inT, E_, N_);
  k_transpose<<<dim3(E_ / 32, N_ / 32), 256, 0, stream>>>(w_out, w_outT, N_, E_);
  k_transpose<<<dim3(V_ / 32, E_ / 32), 256, 0, stream>>>(w_head, w_headT, E_, V_);
  k_gemm_bt<0><<<dim3(N_ / 128, M_ / 128), 256, 0, stream>>>(xg, w_inT, xbuf, b_in, M_, N_, E_);
  k_recurrence<<<RG, 256, 0, stream>>>(xbuf, w_bb, b_bb, u0, u1, sAll, ctr);
  k_layernorm<<<M_, 256, 0, stream>>>(sAll, gamma, beta, hln);
  k_gemm_bt<1><<<dim3(E_ / 128, M_ / 128), 256, 0, stream>>>(hln, w_outT, hw, nullptr, M_, E_, N_);
  k_gemm_bt<2><<<dim3(V_ / 128, M_ / 128), 256, 0, stream>>>(hw, w_headT, out, nullptr, M_, V_, E_);
}